// Round 12
// baseline (274.713 us; speedup 1.0000x reference)
//
#include <hip/hip_runtime.h>
#include <hip/hip_bf16.h>

#define CDIM 384
#define NHEAD 6
#define DHEAD 64
#define BB 16
#define NQ 1024
#define MV 512
#define HIDD 1536
#define KNN 10

typedef __attribute__((ext_vector_type(8))) __bf16 bf16x8;
typedef __attribute__((ext_vector_type(4))) float f32x4;
typedef __attribute__((ext_vector_type(4))) short short4v;

// ---------------- LayerNorm row body (f32 in -> bf16 out, 384 cols, one wave) -----------
__device__ inline void ln_row(const float* __restrict__ xr, const float* __restrict__ gw,
                              const float* __restrict__ bw, __hip_bfloat16* __restrict__ outr,
                              int lane) {
  float v0[6];
  float s = 0.f;
#pragma unroll
  for (int i = 0; i < 3; i++) {
    float2 t = *reinterpret_cast<const float2*>(xr + i * 128 + lane * 2);
    v0[i * 2] = t.x; v0[i * 2 + 1] = t.y; s += t.x + t.y;
  }
  for (int off = 32; off; off >>= 1) s += __shfl_xor(s, off);
  float mean = s * (1.f / 384.f);
  float sq = 0.f;
#pragma unroll
  for (int i = 0; i < 6; i++) { float d = v0[i] - mean; sq += d * d; }
  for (int off = 32; off; off >>= 1) sq += __shfl_xor(sq, off);
  float rstd = rsqrtf(sq * (1.f / 384.f) + 1e-5f);
#pragma unroll
  for (int i = 0; i < 3; i++) {
    int c = i * 128 + lane * 2;
    float2 gg = *reinterpret_cast<const float2*>(gw + c);
    float2 bb = *reinterpret_cast<const float2*>(bw + c);
    __hip_bfloat162 p;
    p.x = __float2bfloat16((v0[i * 2] - mean) * rstd * gg.x + bb.x);
    p.y = __float2bfloat16((v0[i * 2 + 1] - mean) * rstd * gg.y + bb.y);
    *reinterpret_cast<__hip_bfloat162*>(outr + c) = p;
  }
}

// ---------------- prep: all weight transpose-casts + LN1(q) in ONE dispatch -------------
__global__ __launch_bounds__(256) void prep_kernel(
    const float* __restrict__ qkv_w, const float* __restrict__ proj_w,
    const float* __restrict__ knn_w, const float* __restrict__ fc1_w,
    const float* __restrict__ fc2_w, const float* __restrict__ q,
    const float* __restrict__ g1, const float* __restrict__ b1,
    __hip_bfloat16* __restrict__ Wqkv_t, __hip_bfloat16* __restrict__ Wproj_t,
    __hip_bfloat16* __restrict__ W1_t, __hip_bfloat16* __restrict__ Wd_t,
    __hip_bfloat16* __restrict__ Wfc1_t, __hip_bfloat16* __restrict__ Wfc2_t,
    __hip_bfloat16* __restrict__ Xbf) {
  int gid = blockIdx.x;
  if (gid >= 1872) {  // LN1
    int wave = (gid - 1872) * 4 + ((int)threadIdx.x >> 6);
    int lane = threadIdx.x & 63;
    ln_row(q + (size_t)wave * CDIM, g1, b1, Xbf + (size_t)wave * CDIM, lane);
    return;
  }
  __shared__ float t1[32][33];
  __shared__ float t2[32][33];
  int tx = threadIdx.x & 31, ty = (int)threadIdx.x >> 5;
  if (gid >= 576 && gid < 720) {  // knn dual
    int id = gid - 576;
    int k0 = (id % 12) * 32, n0 = (id / 12) * 32;
#pragma unroll
    for (int i = 0; i < 4; i++) {
      int k = k0 + ty + i * 8;
      float w1 = knn_w[(size_t)k * CDIM + n0 + tx];
      float w2 = knn_w[(size_t)(CDIM + k) * CDIM + n0 + tx];
      t1[ty + i * 8][tx] = w1;
      t2[ty + i * 8][tx] = w2 - w1;
    }
    __syncthreads();
#pragma unroll
    for (int i = 0; i < 4; i++) {
      W1_t[(size_t)(n0 + ty + i * 8) * CDIM + k0 + tx] = __float2bfloat16(t1[tx][ty + i * 8]);
      Wd_t[(size_t)(n0 + ty + i * 8) * CDIM + k0 + tx] = __float2bfloat16(t2[tx][ty + i * 8]);
    }
    return;
  }
  const float* W;
  __hip_bfloat16* Wt;
  int Kd, Nd, k0, n0;
  if (gid < 432) {
    W = qkv_w; Wt = Wqkv_t; Kd = 384; Nd = 1152;
    k0 = (gid % 12) * 32; n0 = (gid / 12) * 32;
  } else if (gid < 576) {
    int id = gid - 432;
    W = proj_w; Wt = Wproj_t; Kd = 384; Nd = 384;
    k0 = (id % 12) * 32; n0 = (id / 12) * 32;
  } else if (gid < 1296) {
    int id = gid - 720;
    W = fc1_w; Wt = Wfc1_t; Kd = 384; Nd = 1536;
    k0 = (id % 12) * 32; n0 = (id / 12) * 32;
  } else {
    int id = gid - 1296;
    W = fc2_w; Wt = Wfc2_t; Kd = 1536; Nd = 384;
    k0 = (id % 48) * 32; n0 = (id / 48) * 32;
  }
#pragma unroll
  for (int i = 0; i < 4; i++)
    t1[ty + i * 8][tx] = W[(size_t)(k0 + ty + i * 8) * Nd + n0 + tx];
  __syncthreads();
#pragma unroll
  for (int i = 0; i < 4; i++)
    Wt[(size_t)(n0 + ty + i * 8) * Kd + k0 + tx] = __float2bfloat16(t1[tx][ty + i * 8]);
}

// dual-region LN: waves [0,16384) -> ln(q1)->Xbf ; [16384, 24576) -> ln(v)->NV
__global__ __launch_bounds__(256) void ln_dual_kernel(const float* __restrict__ q1,
                                                      const float* __restrict__ v,
                                                      const float* __restrict__ gq,
                                                      const float* __restrict__ bq,
                                                      const float* __restrict__ gv,
                                                      const float* __restrict__ bv,
                                                      __hip_bfloat16* __restrict__ Xbf,
                                                      __hip_bfloat16* __restrict__ NV) {
  int wave = (int)((blockIdx.x * blockDim.x + threadIdx.x) >> 6);
  int lane = threadIdx.x & 63;
  if (wave < BB * NQ) {
    ln_row(q1 + (size_t)wave * CDIM, gq, bq, Xbf + (size_t)wave * CDIM, lane);
  } else {
    int r = wave - BB * NQ;
    ln_row(v + (size_t)r * CDIM, gv, bv, NV + (size_t)r * CDIM, lane);
  }
}

// ---------------- bf16 GEMM, BMx128 tile (BM=128 or 64), BK=64, gload_lds + XOR swizzle -
// EPI: 0 ->bf16 | 1 bias->f32 | 2 bias+resid->f32 | 3 bias+gelu->bf16 | 4 ->f32
//      5 fused qkv scatter (Q/K/V all via LDS repack, coalesced 16B stores) | 6 merged A1/A2
template <int EPI, int BM>
__global__ __launch_bounds__(256) void gemm_kernel(const __hip_bfloat16* __restrict__ A,
                                                   const __hip_bfloat16* __restrict__ Bt,
                                                   const float* __restrict__ bias,
                                                   const float* __restrict__ resid,
                                                   void* __restrict__ outp,
                                                   void* __restrict__ out2,
                                                   void* __restrict__ out3,
                                                   int M, int N, int Kdim) {
  constexpr int MI = BM / 32;
  constexpr int STAGEB = BM * 64 * 2 + 128 * 64 * 2;
  constexpr int SMEMB = (EPI == 5) ? (128 * 136 * 2 > STAGEB ? 128 * 136 * 2 : STAGEB) : STAGEB;
  __shared__ __align__(16) char smem[SMEMB];
  char* AsB = smem;
  char* BsB = smem + BM * 64 * 2;
  int m0 = blockIdx.y * BM, n0 = blockIdx.x * 128;
  const __hip_bfloat16* Ause = A;
  const __hip_bfloat16* Bt_use = Bt;
  bool isA1 = false;
  if (EPI == 6) {
    constexpr int A2B = 16384 / BM;
    if ((int)blockIdx.y >= A2B) {
      isA1 = true;
      m0 = (blockIdx.y - A2B) * BM;
      Ause = (const __hip_bfloat16*)out3;  // NV
    } else {
      Bt_use = Bt + (size_t)384 * 384;     // Wd (W1 and Wd adjacent in ws)
    }
  }
  int t = threadIdx.x;
  int lane = t & 63, w = t >> 6;
  int wrow = w >> 1, wcol = w & 1;
  int lg = lane >> 4, lr = lane & 15;
  int gcol = (((lane & 7) ^ (lane >> 3)) * 8);
  const __hip_bfloat16* Ab = Ause + (size_t)(m0 + w * 8 + (lane >> 3)) * Kdim + gcol;
  const __hip_bfloat16* Bb = Bt_use + (size_t)(n0 + w * 8 + (lane >> 3)) * Kdim + gcol;
  f32x4 acc[MI][4] = {};
  for (int k0 = 0; k0 < Kdim; k0 += 64) {
    if (k0) __syncthreads();
#pragma unroll
    for (int i = 0; i < MI; i++)
      __builtin_amdgcn_global_load_lds(
          (const __attribute__((address_space(1))) void*)(Ab + (size_t)(i * 32) * Kdim + k0),
          (__attribute__((address_space(3))) void*)(AsB + (i * 4 + w) * 1024), 16, 0, 0);
#pragma unroll
    for (int i = 0; i < 4; i++)
      __builtin_amdgcn_global_load_lds(
          (const __attribute__((address_space(1))) void*)(Bb + (size_t)(i * 32) * Kdim + k0),
          (__attribute__((address_space(3))) void*)(BsB + (i * 4 + w) * 1024), 16, 0, 0);
    __syncthreads();
#pragma unroll
    for (int kk = 0; kk < 2; kk++) {
      bf16x8 a[MI], b[4];
#pragma unroll
      for (int i = 0; i < MI; i++) {
        int ra = wrow * (BM / 2) + i * 16 + lr;
        int sw = (((kk << 2) | lg) ^ (lr & 7)) * 16;
        a[i] = *reinterpret_cast<const bf16x8*>(AsB + ra * 128 + sw);
      }
#pragma unroll
      for (int j = 0; j < 4; j++) {
        int rb = wcol * 64 + j * 16 + lr;
        int sw = (((kk << 2) | lg) ^ (lr & 7)) * 16;
        b[j] = *reinterpret_cast<const bf16x8*>(BsB + rb * 128 + sw);
      }
#pragma unroll
      for (int i = 0; i < MI; i++)
#pragma unroll
        for (int j = 0; j < 4; j++)
          acc[i][j] = __builtin_amdgcn_mfma_f32_16x16x32_bf16(a[i], b[j], acc[i][j], 0, 0, 0);
    }
  }
  if (EPI == 5) {
    // all regions: LDS repack -> coalesced 16B stores. V transposed, Q scaled.
    __syncthreads();
    __hip_bfloat16* S = (__hip_bfloat16*)smem;
    bool isV = (blockIdx.x >= 6);
    float qscale = (blockIdx.x < 3) ? 0.18033688f : 1.f;  // 0.125 * log2(e)
#pragma unroll
    for (int i = 0; i < MI; i++)
#pragma unroll
      for (int j = 0; j < 4; j++) {
        int lc = wcol * 64 + j * 16 + lr;
#pragma unroll
        for (int r = 0; r < 4; r++) {
          int lrow = wrow * 64 + i * 16 + lg * 4 + r;
          float vv = acc[i][j][r] * qscale;
          if (isV) S[lc * 136 + lrow] = __float2bfloat16(vv);
          else S[lrow * 136 + lc] = __float2bfloat16(vv);
        }
      }
    __syncthreads();
    int b = m0 >> 10, nbase = m0 & 1023;
    if (isV) {
      int lc = t >> 1, half = t & 1;
      int c = n0 + lc - 2 * CDIM;
      int h = c >> 6, d = c & 63;
      __hip_bfloat16* dst = (__hip_bfloat16*)out3 +
                            ((size_t)((b * NHEAD + h) * DHEAD + d)) * NQ + nbase + half * 64;
#pragma unroll
      for (int u = 0; u < 8; u++)
        *reinterpret_cast<uint4*>(dst + u * 8) =
            *reinterpret_cast<const uint4*>(&S[lc * 136 + half * 64 + u * 8]);
    } else {
      int rrow = t >> 1, half = t & 1;
      int c0 = n0 - ((int)blockIdx.x < 3 ? 0 : CDIM);
      int h = (c0 >> 6) + half;
      __hip_bfloat16* base = ((int)blockIdx.x < 3) ? (__hip_bfloat16*)outp : (__hip_bfloat16*)out2;
      __hip_bfloat16* dst = base + (((size_t)(b * NHEAD + h)) * NQ + nbase + rrow) * DHEAD;
#pragma unroll
      for (int u = 0; u < 8; u++)
        *reinterpret_cast<uint4*>(dst + u * 8) =
            *reinterpret_cast<const uint4*>(&S[rrow * 136 + half * 64 + u * 8]);
    }
    return;
  }
#pragma unroll
  for (int i = 0; i < MI; i++)
#pragma unroll
    for (int j = 0; j < 4; j++) {
      int col = n0 + wcol * 64 + j * 16 + lr;
#pragma unroll
      for (int r = 0; r < 4; r++) {
        int row = m0 + wrow * (BM / 2) + i * 16 + lg * 4 + r;
        float v = acc[i][j][r];
        if (EPI == 6) {
          float vv = v;
          if (!isA1) vv += bias[col];
          float* dst = isA1 ? (float*)out2 : (float*)outp;
          dst[(size_t)row * 384 + col] = vv;
        } else {
          if (EPI == 1 || EPI == 2 || EPI == 3) v += bias[col];
          if (EPI == 2) v += resid[(size_t)row * N + col];
          if (EPI == 3) v = 0.5f * v * (1.f + erff(v * 0.70710678118654752f));
          if (EPI == 0 || EPI == 3)
            ((__hip_bfloat16*)outp)[(size_t)row * N + col] = __float2bfloat16(v);
          else
            ((float*)outp)[(size_t)row * N + col] = v;
        }
      }
    }
}

// ---------------- flash attention v6: no-max softmax (shift-invariant), LDS dbuf --------
__global__ __launch_bounds__(256) void attn_kernel(const __hip_bfloat16* __restrict__ Qb,
                                                   const __hip_bfloat16* __restrict__ Kb,
                                                   const __hip_bfloat16* __restrict__ Vt,
                                                   __hip_bfloat16* __restrict__ SAb) {
  __shared__ __align__(16) __hip_bfloat16 Ks[2][64][72];
  __shared__ __align__(16) __hip_bfloat16 Vs[2][64][72];
  int bh = blockIdx.x % 96;
  int qblk = blockIdx.x / 96;
  int t = threadIdx.x;
  int w = t >> 6, lane = t & 63;
  int lg = lane >> 4, lr = lane & 15;
  const __hip_bfloat16* Qp = Qb + (size_t)bh * NQ * DHEAD;
  const __hip_bfloat16* Kp = Kb + (size_t)bh * NQ * DHEAD;
  const __hip_bfloat16* Vp = Vt + (size_t)bh * DHEAD * NQ;
  int q0 = qblk * 128 + w * 32;
  bf16x8 qf[2][2];
#pragma unroll
  for (int qt = 0; qt < 2; qt++)
#pragma unroll
    for (int kk = 0; kk < 2; kk++)
      qf[qt][kk] = *reinterpret_cast<const bf16x8*>(
          Qp + (size_t)(q0 + qt * 16 + lr) * DHEAD + kk * 32 + lg * 8);
  int srow = w * 16 + (lane >> 2);
  int scol = (lane & 3) * 16;
  uint4 kr0 = *reinterpret_cast<const uint4*>(Kp + (size_t)srow * DHEAD + scol);
  uint4 kr1 = *reinterpret_cast<const uint4*>(Kp + (size_t)srow * DHEAD + scol + 8);
  uint4 vr0 = *reinterpret_cast<const uint4*>(Vp + (size_t)srow * NQ + scol);
  uint4 vr1 = *reinterpret_cast<const uint4*>(Vp + (size_t)srow * NQ + scol + 8);
  *reinterpret_cast<uint4*>(&Ks[0][srow][scol]) = kr0;
  *reinterpret_cast<uint4*>(&Ks[0][srow][scol + 8]) = kr1;
  *reinterpret_cast<uint4*>(&Vs[0][srow][scol]) = vr0;
  *reinterpret_cast<uint4*>(&Vs[0][srow][scol + 8]) = vr1;
  f32x4 o[2][4] = {};
  float l_[2] = {0.f, 0.f};
  __syncthreads();
  for (int kt = 0; kt < 16; kt++) {
    int cur = kt & 1;
    if (kt < 15) {
      int kb = (kt + 1) * 64;
      kr0 = *reinterpret_cast<const uint4*>(Kp + (size_t)(kb + srow) * DHEAD + scol);
      kr1 = *reinterpret_cast<const uint4*>(Kp + (size_t)(kb + srow) * DHEAD + scol + 8);
      vr0 = *reinterpret_cast<const uint4*>(Vp + (size_t)srow * NQ + kb + scol);
      vr1 = *reinterpret_cast<const uint4*>(Vp + (size_t)srow * NQ + kb + scol + 8);
    }
    f32x4 s[4][2] = {};
#pragma unroll
    for (int kti = 0; kti < 4; kti++)
#pragma unroll
      for (int kk = 0; kk < 2; kk++) {
        bf16x8 a = *reinterpret_cast<const bf16x8*>(&Ks[cur][kti * 16 + lr][kk * 32 + lg * 8]);
#pragma unroll
        for (int qt = 0; qt < 2; qt++)
          s[kti][qt] = __builtin_amdgcn_mfma_f32_16x16x32_bf16(a, qf[qt][kk], s[kti][qt], 0, 0, 0);
      }
#pragma unroll
    for (int qt = 0; qt < 2; qt++) {
      float ls = 0.f;
#pragma unroll
      for (int kti = 0; kti < 4; kti++) {
        float p0 = __builtin_amdgcn_exp2f(s[kti][qt][0]);
        float p1 = __builtin_amdgcn_exp2f(s[kti][qt][1]);
        float p2 = __builtin_amdgcn_exp2f(s[kti][qt][2]);
        float p3 = __builtin_amdgcn_exp2f(s[kti][qt][3]);
        s[kti][qt][0] = p0; s[kti][qt][1] = p1; s[kti][qt][2] = p2; s[kti][qt][3] = p3;
        ls += (p0 + p1) + (p2 + p3);
      }
      l_[qt] += ls;
    }
#pragma unroll
    for (int kti = 0; kti < 4; kti++) {
      short4v pa[2];
#pragma unroll
      for (int qt = 0; qt < 2; qt++) {
#pragma unroll
        for (int r = 0; r < 4; r++) {
          __bf16 hv = (__bf16)s[kti][qt][r];
          pa[qt][r] = __builtin_bit_cast(short, hv);
        }
      }
#pragma unroll
      for (int dt = 0; dt < 4; dt++) {
        short4v vb = *reinterpret_cast<const short4v*>(&Vs[cur][dt * 16 + lr][kti * 16 + lg * 4]);
#pragma unroll
        for (int qt = 0; qt < 2; qt++)
          o[qt][dt] = __builtin_amdgcn_mfma_f32_16x16x16bf16_1k(pa[qt], vb, o[qt][dt], 0, 0, 0);
      }
    }
    if (kt < 15) {
      int nb = cur ^ 1;
      *reinterpret_cast<uint4*>(&Ks[nb][srow][scol]) = kr0;
      *reinterpret_cast<uint4*>(&Ks[nb][srow][scol + 8]) = kr1;
      *reinterpret_cast<uint4*>(&Vs[nb][srow][scol]) = vr0;
      *reinterpret_cast<uint4*>(&Vs[nb][srow][scol + 8]) = vr1;
      __syncthreads();
    }
  }
#pragma unroll
  for (int qt = 0; qt < 2; qt++) {
    l_[qt] += __shfl_xor(l_[qt], 16);
    l_[qt] += __shfl_xor(l_[qt], 32);
  }
  int b = bh / NHEAD, h = bh % NHEAD;
#pragma unroll
  for (int qt = 0; qt < 2; qt++)
#pragma unroll
    for (int r = 0; r < 4; r++) {
      float li = __shfl(l_[qt], (lane & 48) | (((lane >> 4) & 3) * 4 + r));
      float inv = 1.f / li;
      int row = q0 + qt * 16 + ((lane >> 4) & 3) * 4 + r;
#pragma unroll
      for (int dt = 0; dt < 4; dt++)
        SAb[((size_t)(b * NQ + row)) * CDIM + h * DHEAD + dt * 16 + lr] =
            __float2bfloat16(o[qt][dt][r] * inv);
    }
}

// ------- fused: top-K (f32 packed-u64 argmin) + gather/leaky/max + residual + LN2 -------
__global__ __launch_bounds__(256) void knn_fused_kernel(const float* __restrict__ q_pos,
                                                        const float* __restrict__ v_pos,
                                                        const float* __restrict__ A1,
                                                        const float* __restrict__ A2,
                                                        const float* __restrict__ q1,
                                                        const float* __restrict__ g2,
                                                        const float* __restrict__ b2,
                                                        float* __restrict__ q2,
                                                        __hip_bfloat16* __restrict__ xout) {
  int wq = (int)((blockIdx.x * blockDim.x + threadIdx.x) >> 6);
  int lane = threadIdx.x & 63;
  if (wq >= BB * NQ) return;
  int b = wq >> 10;
  const float* qp = q_pos + (size_t)wq * 3;
  float qx = qp[0], qy = qp[1], qz = qp[2];
  float qs = qx * qx + qy * qy + qz * qz;
  unsigned long long pk[8];
#pragma unroll
  for (int j = 0; j < 8; j++) {
    int m = lane + 64 * j;
    const float* vp = v_pos + ((size_t)b * MV + m) * 3;
    float vx = vp[0], vy = vp[1], vz = vp[2];
    float vs = vx * vx + vy * vy + vz * vz;
    float d = qs + vs - 2.f * (qx * vx + qy * vy + qz * vz);
    unsigned ub = __float_as_uint(d);
    ub ^= (unsigned)(((int)ub >> 31)) | 0x80000000u;
    pk[j] = ((unsigned long long)ub << 32) | (unsigned)m;
  }
  unsigned long long lm = pk[0];
#pragma unroll
  for (int j = 1; j < 8; j++) lm = pk[j] < lm ? pk[j] : lm;
  int idxs[KNN];
#pragma unroll
  for (int k = 0; k < KNN; k++) {
    unsigned long long bm = lm;
#pragma unroll
    for (int off = 1; off < 64; off <<= 1) {
      unsigned long long ot = __shfl_xor(bm, off);
      bm = ot < bm ? ot : bm;
    }
    int widx = (int)(unsigned)(bm & 0xFFFFFFFFull);
    idxs[k] = widx;
    if ((widx & 63) == lane) {
      int jj = widx >> 6;
#pragma unroll
      for (int j = 0; j < 8; j++)
        if (j == jj) pk[j] = ~0ull;
      lm = pk[0];
#pragma unroll
      for (int j = 1; j < 8; j++) lm = pk[j] < lm ? pk[j] : lm;
    }
  }
  float a2[6], mx[6];
#pragma unroll
  for (int i = 0; i < 6; i++) {
    a2[i] = A2[(size_t)wq * CDIM + lane + 64 * i];
    mx[i] = -1e30f;
  }
#pragma unroll
  for (int k = 0; k < KNN; k++) {
    const float* a1 = A1 + ((size_t)b * MV + idxs[k]) * CDIM;
#pragma unroll
    for (int i = 0; i < 6; i++) {
      float g = a1[lane + 64 * i] + a2[i];
      g = g > 0.f ? g : 0.2f * g;
      mx[i] = fmaxf(mx[i], g);
    }
  }
  float vals[6];
  float s = 0.f;
#pragma unroll
  for (int i = 0; i < 6; i++) {
    vals[i] = q1[(size_t)wq * CDIM + lane + 64 * i] + mx[i];
    s += vals[i];
  }
  for (int off = 32; off; off >>= 1) s += __shfl_xor(s, off);
  float mean = s * (1.f / 384.f);
  float sq = 0.f;
#pragma unroll
  for (int i = 0; i < 6; i++) { float d = vals[i] - mean; sq += d * d; }
  for (int off = 32; off; off >>= 1) sq += __shfl_xor(sq, off);
  float rstd = rsqrtf(sq * (1.f / 384.f) + 1e-5f);
#pragma unroll
  for (int i = 0; i < 6; i++) {
    int c = lane + 64 * i;
    q2[(size_t)wq * CDIM + c] = vals[i];
    xout[(size_t)wq * CDIM + c] = __float2bfloat16((vals[i] - mean) * rstd * g2[c] + b2[c]);
  }
}

// ---------------------------------- launcher --------------------------------------------
extern "C" void kernel_launch(void* const* d_in, const int* in_sizes, int n_in,
                              void* d_out, int out_size, void* d_ws, size_t ws_size,
                              hipStream_t stream) {
  const float* q = (const float*)d_in[0];
  const float* v = (const float*)d_in[1];
  const float* q_pos = (const float*)d_in[2];
  const float* v_pos = (const float*)d_in[3];
  const float* norm1_g = (const float*)d_in[4];
  const float* norm1_b = (const float*)d_in[5];
  const float* qkv_w = (const float*)d_in[6];
  const float* proj_w = (const float*)d_in[7];
  const float* proj_b = (const float*)d_in[8];
  const float* normq_g = (const float*)d_in[9];
  const float* normq_b = (const float*)d_in[10];
  const float* normv_g = (const float*)d_in[11];
  const float* normv_b = (const float*)d_in[12];
  const float* knn_w = (const float*)d_in[13];
  const float* knn_b = (const float*)d_in[14];
  const float* norm2_g = (const float*)d_in[15];
  const float* norm2_b = (const float*)d_in[16];
  const float* fc1_w = (const float*)d_in[17];
  const float* fc1_b = (const float*)d_in[18];
  const float* fc2_w = (const float*)d_in[19];
  const float* fc2_b = (const float*)d_in[20];

  char* ws = (char*)d_ws;
  const size_t SZ_Wqkv = (size_t)1152 * 384 * 2;
  const size_t SZ_W384 = (size_t)384 * 384 * 2;
  const size_t SZ_Wfc = (size_t)1536 * 384 * 2;
  const size_t SZ_Xbf = (size_t)16384 * 384 * 2;
  const size_t SZ_QKV = (size_t)16384 * 1152 * 2;
  const size_t SZ_q32 = (size_t)16384 * 384 * 4;
  const size_t SZ_NV = (size_t)8192 * 384 * 2;

  size_t o_Wqkv = 0;
  size_t o_Wproj = o_Wqkv + SZ_Wqkv;
  size_t o_W1 = o_Wproj + SZ_W384;
  size_t o_Wd = o_W1 + SZ_W384;      // MUST stay adjacent to W1 (EPI 6 offsets Bt)
  size_t o_Wfc1 = o_Wd + SZ_W384;
  size_t o_Wfc2 = o_Wfc1 + SZ_Wfc;
  size_t o_Xbf = o_Wfc2 + SZ_Wfc;
  size_t o_QKV = o_Xbf + SZ_Xbf;     // region reused: A1f (f32) and A2f (f32)
  size_t o_A1 = o_QKV;
  size_t o_A2 = o_QKV + (size_t)8192 * 384 * 4;
  size_t o_Qb = o_QKV + SZ_QKV;
  size_t o_Kb = o_Qb + SZ_Xbf;
  size_t o_Vt = o_Kb + SZ_Xbf;
  size_t o_SA = o_Vt + SZ_Xbf;
  size_t o_H1 = o_Qb;                // reuse Qb..SA (exactly 16384*1536*2 bytes)
  size_t o_q1 = o_SA + SZ_Xbf;
  size_t o_NV = o_q1 + SZ_q32;
  size_t o_q2 = o_NV + SZ_NV;

  __hip_bfloat16* Wqkv_t = (__hip_bfloat16*)(ws + o_Wqkv);
  __hip_bfloat16* Wproj_t = (__hip_bfloat16*)(ws + o_Wproj);
  __hip_bfloat16* W1_t = (__hip_bfloat16*)(ws + o_W1);
  __hip_bfloat16* Wd_t = (__hip_bfloat16*)(ws + o_Wd);
  __hip_bfloat16* Wfc1_t = (__hip_bfloat16*)(ws + o_Wfc1);
  __hip_bfloat16* Wfc2_t = (__hip_bfloat16*)(ws + o_Wfc2);
  __hip_bfloat16* Xbf = (__hip_bfloat16*)(ws + o_Xbf);
  float* A1f = (float*)(ws + o_A1);
  float* A2f = (float*)(ws + o_A2);
  __hip_bfloat16* Qb = (__hip_bfloat16*)(ws + o_Qb);
  __hip_bfloat16* Kb = (__hip_bfloat16*)(ws + o_Kb);
  __hip_bfloat16* Vt = (__hip_bfloat16*)(ws + o_Vt);
  __hip_bfloat16* SAb = (__hip_bfloat16*)(ws + o_SA);
  __hip_bfloat16* H1 = (__hip_bfloat16*)(ws + o_H1);
  float* q1 = (float*)(ws + o_q1);
  __hip_bfloat16* NV = (__hip_bfloat16*)(ws + o_NV);
  float* q2 = (float*)(ws + o_q2);
  float* outf = (float*)d_out;

  // 1. weights + LN1 in one dispatch
  prep_kernel<<<5968, 256, 0, stream>>>(qkv_w, proj_w, knn_w, fc1_w, fc2_w, q,
                                        norm1_g, norm1_b,
                                        Wqkv_t, Wproj_t, W1_t, Wd_t, Wfc1_t, Wfc2_t, Xbf);
  // 2. qkv gemm fused with head repack (Q/K/V all via LDS repack, coalesced stores)
  gemm_kernel<5, 128><<<dim3(9, 128), 256, 0, stream>>>(Xbf, Wqkv_t, nullptr, nullptr,
                                                        Qb, Kb, Vt, 16384, 1152, 384);
  // 3. attention (768 blocks = 96 bh * 8 qblk)
  attn_kernel<<<768, 256, 0, stream>>>(Qb, Kb, Vt, SAb);
  // 4. proj + bias + residual(q) -> q1  (BM=64: 768 blocks)
  gemm_kernel<2, 64><<<dim3(3, 256), 256, 0, stream>>>(SAb, Wproj_t, proj_b, q, q1,
                                                       nullptr, nullptr, 16384, 384, 384);
  // 5. LN(q1)->Xbf and LN(v)->NV in one dispatch
  ln_dual_kernel<<<6144, 256, 0, stream>>>(q1, v, normq_g, normq_b, normv_g, normv_b, Xbf, NV);
  // 6. merged A2 = Xbf@Wd + knn_b (by<256) and A1 = NV@W1 (by>=256)  (BM=64: 1152 blocks)
  gemm_kernel<6, 64><<<dim3(3, 384), 256, 0, stream>>>(Xbf, W1_t, knn_b, nullptr, A2f,
                                                       A1f, (void*)NV, 16384, 384, 384);
  // 7. fused topk + gather/max + residual + LN2 -> q2, Xbf
  knn_fused_kernel<<<4096, 256, 0, stream>>>(q_pos, v_pos, A1f, A2f, q1,
                                             norm2_g, norm2_b, q2, Xbf);
  // 8. fc1 + gelu -> H1
  gemm_kernel<3, 128><<<dim3(12, 128), 256, 0, stream>>>(Xbf, Wfc1_t, fc1_b, nullptr, H1,
                                                         nullptr, nullptr, 16384, 1536, 384);
  // 9. fc2 + bias + residual(q2) -> out  (BM=64: 768 blocks)
  gemm_kernel<2, 64><<<dim3(3, 256), 256, 0, stream>>>(H1, Wfc2_t, fc2_b, q2, outf,
                                                       nullptr, nullptr, 16384, 384, 1536);
}

// Round 13
// 268.936 us; speedup vs baseline: 1.0215x; 1.0215x over previous
//
#include <hip/hip_runtime.h>
#include <hip/hip_bf16.h>

#define CDIM 384
#define NHEAD 6
#define DHEAD 64
#define BB 16
#define NQ 1024
#define MV 512
#define HIDD 1536
#define KNN 10

typedef __attribute__((ext_vector_type(8))) __bf16 bf16x8;
typedef __attribute__((ext_vector_type(4))) float f32x4;
typedef __attribute__((ext_vector_type(4))) short short4v;

// ---------------- LayerNorm row body (f32 in -> bf16 out, 384 cols, one wave) -----------
__device__ inline void ln_row(const float* __restrict__ xr, const float* __restrict__ gw,
                              const float* __restrict__ bw, __hip_bfloat16* __restrict__ outr,
                              int lane) {
  float v0[6];
  float s = 0.f;
#pragma unroll
  for (int i = 0; i < 3; i++) {
    float2 t = *reinterpret_cast<const float2*>(xr + i * 128 + lane * 2);
    v0[i * 2] = t.x; v0[i * 2 + 1] = t.y; s += t.x + t.y;
  }
  for (int off = 32; off; off >>= 1) s += __shfl_xor(s, off);
  float mean = s * (1.f / 384.f);
  float sq = 0.f;
#pragma unroll
  for (int i = 0; i < 6; i++) { float d = v0[i] - mean; sq += d * d; }
  for (int off = 32; off; off >>= 1) sq += __shfl_xor(sq, off);
  float rstd = rsqrtf(sq * (1.f / 384.f) + 1e-5f);
#pragma unroll
  for (int i = 0; i < 3; i++) {
    int c = i * 128 + lane * 2;
    float2 gg = *reinterpret_cast<const float2*>(gw + c);
    float2 bb = *reinterpret_cast<const float2*>(bw + c);
    __hip_bfloat162 p;
    p.x = __float2bfloat16((v0[i * 2] - mean) * rstd * gg.x + bb.x);
    p.y = __float2bfloat16((v0[i * 2 + 1] - mean) * rstd * gg.y + bb.y);
    *reinterpret_cast<__hip_bfloat162*>(outr + c) = p;
  }
}

// ---------------- prep: all weight transpose-casts + LN1(q) in ONE dispatch -------------
__global__ __launch_bounds__(256) void prep_kernel(
    const float* __restrict__ qkv_w, const float* __restrict__ proj_w,
    const float* __restrict__ knn_w, const float* __restrict__ fc1_w,
    const float* __restrict__ fc2_w, const float* __restrict__ q,
    const float* __restrict__ g1, const float* __restrict__ b1,
    __hip_bfloat16* __restrict__ Wqkv_t, __hip_bfloat16* __restrict__ Wproj_t,
    __hip_bfloat16* __restrict__ W1_t, __hip_bfloat16* __restrict__ Wd_t,
    __hip_bfloat16* __restrict__ Wfc1_t, __hip_bfloat16* __restrict__ Wfc2_t,
    __hip_bfloat16* __restrict__ Xbf) {
  int gid = blockIdx.x;
  if (gid >= 1872) {  // LN1
    int wave = (gid - 1872) * 4 + ((int)threadIdx.x >> 6);
    int lane = threadIdx.x & 63;
    ln_row(q + (size_t)wave * CDIM, g1, b1, Xbf + (size_t)wave * CDIM, lane);
    return;
  }
  __shared__ float t1[32][33];
  __shared__ float t2[32][33];
  int tx = threadIdx.x & 31, ty = (int)threadIdx.x >> 5;
  if (gid >= 576 && gid < 720) {  // knn dual
    int id = gid - 576;
    int k0 = (id % 12) * 32, n0 = (id / 12) * 32;
#pragma unroll
    for (int i = 0; i < 4; i++) {
      int k = k0 + ty + i * 8;
      float w1 = knn_w[(size_t)k * CDIM + n0 + tx];
      float w2 = knn_w[(size_t)(CDIM + k) * CDIM + n0 + tx];
      t1[ty + i * 8][tx] = w1;
      t2[ty + i * 8][tx] = w2 - w1;
    }
    __syncthreads();
#pragma unroll
    for (int i = 0; i < 4; i++) {
      W1_t[(size_t)(n0 + ty + i * 8) * CDIM + k0 + tx] = __float2bfloat16(t1[tx][ty + i * 8]);
      Wd_t[(size_t)(n0 + ty + i * 8) * CDIM + k0 + tx] = __float2bfloat16(t2[tx][ty + i * 8]);
    }
    return;
  }
  const float* W;
  __hip_bfloat16* Wt;
  int Kd, Nd, k0, n0;
  if (gid < 432) {
    W = qkv_w; Wt = Wqkv_t; Kd = 384; Nd = 1152;
    k0 = (gid % 12) * 32; n0 = (gid / 12) * 32;
  } else if (gid < 576) {
    int id = gid - 432;
    W = proj_w; Wt = Wproj_t; Kd = 384; Nd = 384;
    k0 = (id % 12) * 32; n0 = (id / 12) * 32;
  } else if (gid < 1296) {
    int id = gid - 720;
    W = fc1_w; Wt = Wfc1_t; Kd = 384; Nd = 1536;
    k0 = (id % 12) * 32; n0 = (id / 12) * 32;
  } else {
    int id = gid - 1296;
    W = fc2_w; Wt = Wfc2_t; Kd = 1536; Nd = 384;
    k0 = (id % 48) * 32; n0 = (id / 48) * 32;
  }
#pragma unroll
  for (int i = 0; i < 4; i++)
    t1[ty + i * 8][tx] = W[(size_t)(k0 + ty + i * 8) * Nd + n0 + tx];
  __syncthreads();
#pragma unroll
  for (int i = 0; i < 4; i++)
    Wt[(size_t)(n0 + ty + i * 8) * Kd + k0 + tx] = __float2bfloat16(t1[tx][ty + i * 8]);
}

// dual-region LN: waves [0,16384) -> ln(q1)->Xbf ; [16384, 24576) -> ln(v)->NV
__global__ __launch_bounds__(256) void ln_dual_kernel(const float* __restrict__ q1,
                                                      const float* __restrict__ v,
                                                      const float* __restrict__ gq,
                                                      const float* __restrict__ bq,
                                                      const float* __restrict__ gv,
                                                      const float* __restrict__ bv,
                                                      __hip_bfloat16* __restrict__ Xbf,
                                                      __hip_bfloat16* __restrict__ NV) {
  int wave = (int)((blockIdx.x * blockDim.x + threadIdx.x) >> 6);
  int lane = threadIdx.x & 63;
  if (wave < BB * NQ) {
    ln_row(q1 + (size_t)wave * CDIM, gq, bq, Xbf + (size_t)wave * CDIM, lane);
  } else {
    int r = wave - BB * NQ;
    ln_row(v + (size_t)r * CDIM, gv, bv, NV + (size_t)r * CDIM, lane);
  }
}

// ---------------- bf16 GEMM, BMx128 tile (BM=128 or 64), BK=64, gload_lds + XOR swizzle -
// EPI: 0 ->bf16 | 1 bias->f32 | 2 bias+resid->f32 | 3 bias+gelu->bf16 | 4 ->f32
//      5 fused qkv scatter (V cols transposed via LDS) | 6 merged A1/A2
template <int EPI, int BM>
__global__ __launch_bounds__(256) void gemm_kernel(const __hip_bfloat16* __restrict__ A,
                                                   const __hip_bfloat16* __restrict__ Bt,
                                                   const float* __restrict__ bias,
                                                   const float* __restrict__ resid,
                                                   void* __restrict__ outp,
                                                   void* __restrict__ out2,
                                                   void* __restrict__ out3,
                                                   int M, int N, int Kdim) {
  constexpr int MI = BM / 32;
  constexpr int STAGEB = BM * 64 * 2 + 128 * 64 * 2;
  constexpr int SMEMB = (EPI == 5) ? (128 * 136 * 2 > STAGEB ? 128 * 136 * 2 : STAGEB) : STAGEB;
  __shared__ __align__(16) char smem[SMEMB];
  char* AsB = smem;
  char* BsB = smem + BM * 64 * 2;
  int m0 = blockIdx.y * BM, n0 = blockIdx.x * 128;
  const __hip_bfloat16* Ause = A;
  const __hip_bfloat16* Bt_use = Bt;
  bool isA1 = false;
  if (EPI == 6) {
    constexpr int A2B = 16384 / BM;
    if ((int)blockIdx.y >= A2B) {
      isA1 = true;
      m0 = (blockIdx.y - A2B) * BM;
      Ause = (const __hip_bfloat16*)out3;  // NV
    } else {
      Bt_use = Bt + (size_t)384 * 384;     // Wd (W1 and Wd adjacent in ws)
    }
  }
  int t = threadIdx.x;
  int lane = t & 63, w = t >> 6;
  int wrow = w >> 1, wcol = w & 1;
  int lg = lane >> 4, lr = lane & 15;
  int gcol = (((lane & 7) ^ (lane >> 3)) * 8);
  const __hip_bfloat16* Ab = Ause + (size_t)(m0 + w * 8 + (lane >> 3)) * Kdim + gcol;
  const __hip_bfloat16* Bb = Bt_use + (size_t)(n0 + w * 8 + (lane >> 3)) * Kdim + gcol;
  f32x4 acc[MI][4] = {};
  for (int k0 = 0; k0 < Kdim; k0 += 64) {
    if (k0) __syncthreads();
#pragma unroll
    for (int i = 0; i < MI; i++)
      __builtin_amdgcn_global_load_lds(
          (const __attribute__((address_space(1))) void*)(Ab + (size_t)(i * 32) * Kdim + k0),
          (__attribute__((address_space(3))) void*)(AsB + (i * 4 + w) * 1024), 16, 0, 0);
#pragma unroll
    for (int i = 0; i < 4; i++)
      __builtin_amdgcn_global_load_lds(
          (const __attribute__((address_space(1))) void*)(Bb + (size_t)(i * 32) * Kdim + k0),
          (__attribute__((address_space(3))) void*)(BsB + (i * 4 + w) * 1024), 16, 0, 0);
    __syncthreads();
#pragma unroll
    for (int kk = 0; kk < 2; kk++) {
      bf16x8 a[MI], b[4];
#pragma unroll
      for (int i = 0; i < MI; i++) {
        int ra = wrow * (BM / 2) + i * 16 + lr;
        int sw = (((kk << 2) | lg) ^ (lr & 7)) * 16;
        a[i] = *reinterpret_cast<const bf16x8*>(AsB + ra * 128 + sw);
      }
#pragma unroll
      for (int j = 0; j < 4; j++) {
        int rb = wcol * 64 + j * 16 + lr;
        int sw = (((kk << 2) | lg) ^ (lr & 7)) * 16;
        b[j] = *reinterpret_cast<const bf16x8*>(BsB + rb * 128 + sw);
      }
#pragma unroll
      for (int i = 0; i < MI; i++)
#pragma unroll
        for (int j = 0; j < 4; j++)
          acc[i][j] = __builtin_amdgcn_mfma_f32_16x16x32_bf16(a[i], b[j], acc[i][j], 0, 0, 0);
    }
  }
  if (EPI == 5 && blockIdx.x >= 6) {
    // V columns: transpose 128x128 quadrants via LDS, then coalesced 16B stores
    __syncthreads();
    __hip_bfloat16* S = (__hip_bfloat16*)smem;
#pragma unroll
    for (int i = 0; i < MI; i++)
#pragma unroll
      for (int j = 0; j < 4; j++) {
        int lc = wcol * 64 + j * 16 + lr;
#pragma unroll
        for (int r = 0; r < 4; r++) {
          int lrow = wrow * 64 + i * 16 + lg * 4 + r;
          S[lc * 136 + lrow] = __float2bfloat16(acc[i][j][r]);
        }
      }
    __syncthreads();
    int b = m0 >> 10, nbase = m0 & 1023;
    int lc = t >> 1, half = t & 1;
    int c = n0 + lc - 2 * CDIM;
    int h = c >> 6, d = c & 63;
    __hip_bfloat16* dst = (__hip_bfloat16*)out3 +
                          ((size_t)((b * NHEAD + h) * DHEAD + d)) * NQ + nbase + half * 64;
#pragma unroll
    for (int u = 0; u < 8; u++)
      *reinterpret_cast<uint4*>(dst + u * 8) =
          *reinterpret_cast<const uint4*>(&S[lc * 136 + half * 64 + u * 8]);
    return;
  }
#pragma unroll
  for (int i = 0; i < MI; i++)
#pragma unroll
    for (int j = 0; j < 4; j++) {
      int col = n0 + wcol * 64 + j * 16 + lr;
#pragma unroll
      for (int r = 0; r < 4; r++) {
        int row = m0 + wrow * (BM / 2) + i * 16 + lg * 4 + r;
        float v = acc[i][j][r];
        if (EPI == 5) {
          int b = row >> 10, n = row & 1023;
          if (col < CDIM) {
            int h = col >> 6, d = col & 63;
            ((__hip_bfloat16*)outp)[(((size_t)(b * NHEAD + h)) * NQ + n) * DHEAD + d] =
                __float2bfloat16(v * 0.18033688f);  // 0.125 * log2(e)
          } else {
            int c = col - CDIM, h = c >> 6, d = c & 63;
            ((__hip_bfloat16*)out2)[(((size_t)(b * NHEAD + h)) * NQ + n) * DHEAD + d] =
                __float2bfloat16(v);
          }
        } else if (EPI == 6) {
          float vv = v;
          if (!isA1) vv += bias[col];
          float* dst = isA1 ? (float*)out2 : (float*)outp;
          dst[(size_t)row * 384 + col] = vv;
        } else {
          if (EPI == 1 || EPI == 2 || EPI == 3) v += bias[col];
          if (EPI == 2) v += resid[(size_t)row * N + col];
          if (EPI == 3) v = 0.5f * v * (1.f + erff(v * 0.70710678118654752f));
          if (EPI == 0 || EPI == 3)
            ((__hip_bfloat16*)outp)[(size_t)row * N + col] = __float2bfloat16(v);
          else
            ((float*)outp)[(size_t)row * N + col] = v;
        }
      }
    }
}

// ---------------- flash attention v6: no-max softmax (shift-invariant), LDS dbuf --------
__global__ __launch_bounds__(256) void attn_kernel(const __hip_bfloat16* __restrict__ Qb,
                                                   const __hip_bfloat16* __restrict__ Kb,
                                                   const __hip_bfloat16* __restrict__ Vt,
                                                   __hip_bfloat16* __restrict__ SAb) {
  __shared__ __align__(16) __hip_bfloat16 Ks[2][64][72];
  __shared__ __align__(16) __hip_bfloat16 Vs[2][64][72];
  int bh = blockIdx.x % 96;
  int qblk = blockIdx.x / 96;
  int t = threadIdx.x;
  int w = t >> 6, lane = t & 63;
  int lg = lane >> 4, lr = lane & 15;
  const __hip_bfloat16* Qp = Qb + (size_t)bh * NQ * DHEAD;
  const __hip_bfloat16* Kp = Kb + (size_t)bh * NQ * DHEAD;
  const __hip_bfloat16* Vp = Vt + (size_t)bh * DHEAD * NQ;
  int q0 = qblk * 128 + w * 32;
  bf16x8 qf[2][2];
#pragma unroll
  for (int qt = 0; qt < 2; qt++)
#pragma unroll
    for (int kk = 0; kk < 2; kk++)
      qf[qt][kk] = *reinterpret_cast<const bf16x8*>(
          Qp + (size_t)(q0 + qt * 16 + lr) * DHEAD + kk * 32 + lg * 8);
  int srow = w * 16 + (lane >> 2);
  int scol = (lane & 3) * 16;
  uint4 kr0 = *reinterpret_cast<const uint4*>(Kp + (size_t)srow * DHEAD + scol);
  uint4 kr1 = *reinterpret_cast<const uint4*>(Kp + (size_t)srow * DHEAD + scol + 8);
  uint4 vr0 = *reinterpret_cast<const uint4*>(Vp + (size_t)srow * NQ + scol);
  uint4 vr1 = *reinterpret_cast<const uint4*>(Vp + (size_t)srow * NQ + scol + 8);
  *reinterpret_cast<uint4*>(&Ks[0][srow][scol]) = kr0;
  *reinterpret_cast<uint4*>(&Ks[0][srow][scol + 8]) = kr1;
  *reinterpret_cast<uint4*>(&Vs[0][srow][scol]) = vr0;
  *reinterpret_cast<uint4*>(&Vs[0][srow][scol + 8]) = vr1;
  f32x4 o[2][4] = {};
  float l_[2] = {0.f, 0.f};
  __syncthreads();
  for (int kt = 0; kt < 16; kt++) {
    int cur = kt & 1;
    if (kt < 15) {
      int kb = (kt + 1) * 64;
      kr0 = *reinterpret_cast<const uint4*>(Kp + (size_t)(kb + srow) * DHEAD + scol);
      kr1 = *reinterpret_cast<const uint4*>(Kp + (size_t)(kb + srow) * DHEAD + scol + 8);
      vr0 = *reinterpret_cast<const uint4*>(Vp + (size_t)srow * NQ + kb + scol);
      vr1 = *reinterpret_cast<const uint4*>(Vp + (size_t)srow * NQ + kb + scol + 8);
    }
    f32x4 s[4][2] = {};
#pragma unroll
    for (int kti = 0; kti < 4; kti++)
#pragma unroll
      for (int kk = 0; kk < 2; kk++) {
        bf16x8 a = *reinterpret_cast<const bf16x8*>(&Ks[cur][kti * 16 + lr][kk * 32 + lg * 8]);
#pragma unroll
        for (int qt = 0; qt < 2; qt++)
          s[kti][qt] = __builtin_amdgcn_mfma_f32_16x16x32_bf16(a, qf[qt][kk], s[kti][qt], 0, 0, 0);
      }
#pragma unroll
    for (int qt = 0; qt < 2; qt++) {
      float ls = 0.f;
#pragma unroll
      for (int kti = 0; kti < 4; kti++) {
        float p0 = __builtin_amdgcn_exp2f(s[kti][qt][0]);
        float p1 = __builtin_amdgcn_exp2f(s[kti][qt][1]);
        float p2 = __builtin_amdgcn_exp2f(s[kti][qt][2]);
        float p3 = __builtin_amdgcn_exp2f(s[kti][qt][3]);
        s[kti][qt][0] = p0; s[kti][qt][1] = p1; s[kti][qt][2] = p2; s[kti][qt][3] = p3;
        ls += (p0 + p1) + (p2 + p3);
      }
      l_[qt] += ls;
    }
#pragma unroll
    for (int kti = 0; kti < 4; kti++) {
      short4v pa[2];
#pragma unroll
      for (int qt = 0; qt < 2; qt++) {
#pragma unroll
        for (int r = 0; r < 4; r++) {
          __bf16 hv = (__bf16)s[kti][qt][r];
          pa[qt][r] = __builtin_bit_cast(short, hv);
        }
      }
#pragma unroll
      for (int dt = 0; dt < 4; dt++) {
        short4v vb = *reinterpret_cast<const short4v*>(&Vs[cur][dt * 16 + lr][kti * 16 + lg * 4]);
#pragma unroll
        for (int qt = 0; qt < 2; qt++)
          o[qt][dt] = __builtin_amdgcn_mfma_f32_16x16x16bf16_1k(pa[qt], vb, o[qt][dt], 0, 0, 0);
      }
    }
    if (kt < 15) {
      int nb = cur ^ 1;
      *reinterpret_cast<uint4*>(&Ks[nb][srow][scol]) = kr0;
      *reinterpret_cast<uint4*>(&Ks[nb][srow][scol + 8]) = kr1;
      *reinterpret_cast<uint4*>(&Vs[nb][srow][scol]) = vr0;
      *reinterpret_cast<uint4*>(&Vs[nb][srow][scol + 8]) = vr1;
      __syncthreads();
    }
  }
#pragma unroll
  for (int qt = 0; qt < 2; qt++) {
    l_[qt] += __shfl_xor(l_[qt], 16);
    l_[qt] += __shfl_xor(l_[qt], 32);
  }
  int b = bh / NHEAD, h = bh % NHEAD;
#pragma unroll
  for (int qt = 0; qt < 2; qt++)
#pragma unroll
    for (int r = 0; r < 4; r++) {
      float li = __shfl(l_[qt], (lane & 48) | (((lane >> 4) & 3) * 4 + r));
      float inv = 1.f / li;
      int row = q0 + qt * 16 + ((lane >> 4) & 3) * 4 + r;
#pragma unroll
      for (int dt = 0; dt < 4; dt++)
        SAb[((size_t)(b * NQ + row)) * CDIM + h * DHEAD + dt * 16 + lr] =
            __float2bfloat16(o[qt][dt][r] * inv);
    }
}

// ------- fused: top-K (f32 packed-u64 argmin) + gather/leaky/max + residual + LN2 -------
__global__ __launch_bounds__(256) void knn_fused_kernel(const float* __restrict__ q_pos,
                                                        const float* __restrict__ v_pos,
                                                        const float* __restrict__ A1,
                                                        const float* __restrict__ A2,
                                                        const float* __restrict__ q1,
                                                        const float* __restrict__ g2,
                                                        const float* __restrict__ b2,
                                                        float* __restrict__ q2,
                                                        __hip_bfloat16* __restrict__ xout) {
  int wq = (int)((blockIdx.x * blockDim.x + threadIdx.x) >> 6);
  int lane = threadIdx.x & 63;
  if (wq >= BB * NQ) return;
  int b = wq >> 10;
  const float* qp = q_pos + (size_t)wq * 3;
  float qx = qp[0], qy = qp[1], qz = qp[2];
  float qs = qx * qx + qy * qy + qz * qz;
  unsigned long long pk[8];
#pragma unroll
  for (int j = 0; j < 8; j++) {
    int m = lane + 64 * j;
    const float* vp = v_pos + ((size_t)b * MV + m) * 3;
    float vx = vp[0], vy = vp[1], vz = vp[2];
    float vs = vx * vx + vy * vy + vz * vz;
    float d = qs + vs - 2.f * (qx * vx + qy * vy + qz * vz);
    unsigned ub = __float_as_uint(d);
    ub ^= (unsigned)(((int)ub >> 31)) | 0x80000000u;
    pk[j] = ((unsigned long long)ub << 32) | (unsigned)m;
  }
  unsigned long long lm = pk[0];
#pragma unroll
  for (int j = 1; j < 8; j++) lm = pk[j] < lm ? pk[j] : lm;
  int idxs[KNN];
#pragma unroll
  for (int k = 0; k < KNN; k++) {
    unsigned long long bm = lm;
#pragma unroll
    for (int off = 1; off < 64; off <<= 1) {
      unsigned long long ot = __shfl_xor(bm, off);
      bm = ot < bm ? ot : bm;
    }
    int widx = (int)(unsigned)(bm & 0xFFFFFFFFull);
    idxs[k] = widx;
    if ((widx & 63) == lane) {
      int jj = widx >> 6;
#pragma unroll
      for (int j = 0; j < 8; j++)
        if (j == jj) pk[j] = ~0ull;
      lm = pk[0];
#pragma unroll
      for (int j = 1; j < 8; j++) lm = pk[j] < lm ? pk[j] : lm;
    }
  }
  float a2[6], mx[6];
#pragma unroll
  for (int i = 0; i < 6; i++) {
    a2[i] = A2[(size_t)wq * CDIM + lane + 64 * i];
    mx[i] = -1e30f;
  }
#pragma unroll
  for (int k = 0; k < KNN; k++) {
    const float* a1 = A1 + ((size_t)b * MV + idxs[k]) * CDIM;
#pragma unroll
    for (int i = 0; i < 6; i++) {
      float g = a1[lane + 64 * i] + a2[i];
      g = g > 0.f ? g : 0.2f * g;
      mx[i] = fmaxf(mx[i], g);
    }
  }
  float vals[6];
  float s = 0.f;
#pragma unroll
  for (int i = 0; i < 6; i++) {
    vals[i] = q1[(size_t)wq * CDIM + lane + 64 * i] + mx[i];
    s += vals[i];
  }
  for (int off = 32; off; off >>= 1) s += __shfl_xor(s, off);
  float mean = s * (1.f / 384.f);
  float sq = 0.f;
#pragma unroll
  for (int i = 0; i < 6; i++) { float d = vals[i] - mean; sq += d * d; }
  for (int off = 32; off; off >>= 1) sq += __shfl_xor(sq, off);
  float rstd = rsqrtf(sq * (1.f / 384.f) + 1e-5f);
#pragma unroll
  for (int i = 0; i < 6; i++) {
    int c = lane + 64 * i;
    q2[(size_t)wq * CDIM + c] = vals[i];
    xout[(size_t)wq * CDIM + c] = __float2bfloat16((vals[i] - mean) * rstd * g2[c] + b2[c]);
  }
}

// ---------------------------------- launcher --------------------------------------------
extern "C" void kernel_launch(void* const* d_in, const int* in_sizes, int n_in,
                              void* d_out, int out_size, void* d_ws, size_t ws_size,
                              hipStream_t stream) {
  const float* q = (const float*)d_in[0];
  const float* v = (const float*)d_in[1];
  const float* q_pos = (const float*)d_in[2];
  const float* v_pos = (const float*)d_in[3];
  const float* norm1_g = (const float*)d_in[4];
  const float* norm1_b = (const float*)d_in[5];
  const float* qkv_w = (const float*)d_in[6];
  const float* proj_w = (const float*)d_in[7];
  const float* proj_b = (const float*)d_in[8];
  const float* normq_g = (const float*)d_in[9];
  const float* normq_b = (const float*)d_in[10];
  const float* normv_g = (const float*)d_in[11];
  const float* normv_b = (const float*)d_in[12];
  const float* knn_w = (const float*)d_in[13];
  const float* knn_b = (const float*)d_in[14];
  const float* norm2_g = (const float*)d_in[15];
  const float* norm2_b = (const float*)d_in[16];
  const float* fc1_w = (const float*)d_in[17];
  const float* fc1_b = (const float*)d_in[18];
  const float* fc2_w = (const float*)d_in[19];
  const float* fc2_b = (const float*)d_in[20];

  char* ws = (char*)d_ws;
  const size_t SZ_Wqkv = (size_t)1152 * 384 * 2;
  const size_t SZ_W384 = (size_t)384 * 384 * 2;
  const size_t SZ_Wfc = (size_t)1536 * 384 * 2;
  const size_t SZ_Xbf = (size_t)16384 * 384 * 2;
  const size_t SZ_QKV = (size_t)16384 * 1152 * 2;
  const size_t SZ_q32 = (size_t)16384 * 384 * 4;
  const size_t SZ_NV = (size_t)8192 * 384 * 2;

  size_t o_Wqkv = 0;
  size_t o_Wproj = o_Wqkv + SZ_Wqkv;
  size_t o_W1 = o_Wproj + SZ_W384;
  size_t o_Wd = o_W1 + SZ_W384;      // MUST stay adjacent to W1 (EPI 6 offsets Bt)
  size_t o_Wfc1 = o_Wd + SZ_W384;
  size_t o_Wfc2 = o_Wfc1 + SZ_Wfc;
  size_t o_Xbf = o_Wfc2 + SZ_Wfc;
  size_t o_QKV = o_Xbf + SZ_Xbf;     // region reused: A1f (f32) and A2f (f32)
  size_t o_A1 = o_QKV;
  size_t o_A2 = o_QKV + (size_t)8192 * 384 * 4;
  size_t o_Qb = o_QKV + SZ_QKV;
  size_t o_Kb = o_Qb + SZ_Xbf;
  size_t o_Vt = o_Kb + SZ_Xbf;
  size_t o_SA = o_Vt + SZ_Xbf;
  size_t o_H1 = o_Qb;                // reuse Qb..SA (exactly 16384*1536*2 bytes)
  size_t o_q1 = o_SA + SZ_Xbf;
  size_t o_NV = o_q1 + SZ_q32;
  size_t o_q2 = o_NV + SZ_NV;

  __hip_bfloat16* Wqkv_t = (__hip_bfloat16*)(ws + o_Wqkv);
  __hip_bfloat16* Wproj_t = (__hip_bfloat16*)(ws + o_Wproj);
  __hip_bfloat16* W1_t = (__hip_bfloat16*)(ws + o_W1);
  __hip_bfloat16* Wd_t = (__hip_bfloat16*)(ws + o_Wd);
  __hip_bfloat16* Wfc1_t = (__hip_bfloat16*)(ws + o_Wfc1);
  __hip_bfloat16* Wfc2_t = (__hip_bfloat16*)(ws + o_Wfc2);
  __hip_bfloat16* Xbf = (__hip_bfloat16*)(ws + o_Xbf);
  float* A1f = (float*)(ws + o_A1);
  float* A2f = (float*)(ws + o_A2);
  __hip_bfloat16* Qb = (__hip_bfloat16*)(ws + o_Qb);
  __hip_bfloat16* Kb = (__hip_bfloat16*)(ws + o_Kb);
  __hip_bfloat16* Vt = (__hip_bfloat16*)(ws + o_Vt);
  __hip_bfloat16* SAb = (__hip_bfloat16*)(ws + o_SA);
  __hip_bfloat16* H1 = (__hip_bfloat16*)(ws + o_H1);
  float* q1 = (float*)(ws + o_q1);
  __hip_bfloat16* NV = (__hip_bfloat16*)(ws + o_NV);
  float* q2 = (float*)(ws + o_q2);
  float* outf = (float*)d_out;

  // 1. weights + LN1 in one dispatch
  prep_kernel<<<5968, 256, 0, stream>>>(qkv_w, proj_w, knn_w, fc1_w, fc2_w, q,
                                        norm1_g, norm1_b,
                                        Wqkv_t, Wproj_t, W1_t, Wd_t, Wfc1_t, Wfc2_t, Xbf);
  // 2. qkv gemm fused with head repack (Qb scaled incl. log2e, Kb, Vt via LDS transpose)
  gemm_kernel<5, 128><<<dim3(9, 128), 256, 0, stream>>>(Xbf, Wqkv_t, nullptr, nullptr,
                                                        Qb, Kb, Vt, 16384, 1152, 384);
  // 3. attention (768 blocks = 96 bh * 8 qblk)
  attn_kernel<<<768, 256, 0, stream>>>(Qb, Kb, Vt, SAb);
  // 4. proj + bias + residual(q) -> q1  (BM=64: 768 blocks)
  gemm_kernel<2, 64><<<dim3(3, 256), 256, 0, stream>>>(SAb, Wproj_t, proj_b, q, q1,
                                                       nullptr, nullptr, 16384, 384, 384);
  // 5. LN(q1)->Xbf and LN(v)->NV in one dispatch
  ln_dual_kernel<<<6144, 256, 0, stream>>>(q1, v, normq_g, normq_b, normv_g, normv_b, Xbf, NV);
  // 6. merged A2 = Xbf@Wd + knn_b (by<256) and A1 = NV@W1 (by>=256)  (BM=64: 1152 blocks)
  gemm_kernel<6, 64><<<dim3(3, 384), 256, 0, stream>>>(Xbf, W1_t, knn_b, nullptr, A2f,
                                                       A1f, (void*)NV, 16384, 384, 384);
  // 7. fused topk + gather/max + residual + LN2 -> q2, Xbf
  knn_fused_kernel<<<4096, 256, 0, stream>>>(q_pos, v_pos, A1f, A2f, q1,
                                             norm2_g, norm2_b, q2, Xbf);
  // 8. fc1 + gelu -> H1
  gemm_kernel<3, 128><<<dim3(12, 128), 256, 0, stream>>>(Xbf, Wfc1_t, fc1_b, nullptr, H1,
                                                         nullptr, nullptr, 16384, 1536, 384);
  // 9. fc2 + bias + residual(q2) -> out  (BM=64: 768 blocks)
  gemm_kernel<2, 64><<<dim3(3, 256), 256, 0, stream>>>(H1, Wfc2_t, fc2_b, q2, outf,
                                                       nullptr, nullptr, 16384, 384, 1536);
}